// Round 1
// baseline (450.945 us; speedup 1.0000x reference)
//
#include <hip/hip_runtime.h>

// Problem constants (fixed by the reference):
#define E_ENV 8192
#define A_AG  128
#define K_PASS 512
#define P_TOT (E_ENV * K_PASS)   // 4,194,304 passengers

// ---------------------------------------------------------------------------
// Kernel 1: per-(env,agent) staging.
//  - distance (inf for invalid all -100 rows)
//  - accept_t = accepts ? target : -100 ; count[target]++ for valid
//  - pick success (d < 1e-6) -> picked[target] = 1  (multi-writer same value, OK)
// ---------------------------------------------------------------------------
__global__ __launch_bounds__(256) void k_stage(
    const int* __restrict__ accepts, const int* __restrict__ picks,
    const int* __restrict__ targets, const float4* __restrict__ vectors,
    int* __restrict__ counts, float* __restrict__ dist,
    int* __restrict__ accept_t, unsigned char* __restrict__ picked)
{
    int tid = blockIdx.x * 256 + threadIdx.x;   // < E_ENV*A_AG
    float4 v = vectors[tid];
    bool invalid = (v.x == -100.0f) && (v.y == -100.0f) &&
                   (v.z == -100.0f) && (v.w == -100.0f);
    float dx = v.x - v.z, dy = v.y - v.w;
    float d = sqrtf(dx * dx + dy * dy);
    if (invalid) d = INFINITY;
    dist[tid] = d;

    int t  = targets[tid];
    int at = accepts[tid] ? t : -100;
    accept_t[tid] = at;
    if (at >= 0) atomicAdd(&counts[at], 1);

    // pick transition: only zero-distance picks succeed
    if (picks[tid] && d < 1e-6f) picked[t] = 1;
}

// ---------------------------------------------------------------------------
// Kernel 2: per-env conflict resolution (the while_loop runs exactly once).
// One wave (64 lanes) per env; each lane owns agents l and l+64.
// dup = count[t]>1 ; survivor = argmin over (dup ? dist : inf), first-index
// tie-break (matches jnp.argmin). All other dup agents -> -100.
// Surviving valid targets are unique per passenger -> plain byte store.
// ---------------------------------------------------------------------------
__global__ __launch_bounds__(64) void k_resolve(
    const int* __restrict__ counts, const float* __restrict__ dist,
    const int* __restrict__ accept_t, unsigned char* __restrict__ acc_agent)
{
    int e = blockIdx.x;
    int l = threadIdx.x;          // 0..63
    int base = e * A_AG;
    int a0 = l, a1 = l + 64;

    int t0 = accept_t[base + a0];
    int t1 = accept_t[base + a1];
    bool dup0 = (t0 >= 0) && (counts[t0] > 1);
    bool dup1 = (t1 >= 0) && (counts[t1] > 1);
    float e0 = dup0 ? dist[base + a0] : INFINITY;
    float e1 = dup1 ? dist[base + a1] : INFINITY;

    // local best (value, index): strictly smaller value wins; tie -> smaller idx
    float bv; int bi;
    if (e1 < e0) { bv = e1; bi = a1; } else { bv = e0; bi = a0; }

    // wave-64 butterfly argmin
    #pragma unroll
    for (int off = 32; off > 0; off >>= 1) {
        float ov = __shfl_xor(bv, off);
        int   oi = __shfl_xor(bi, off);
        if (ov < bv || (ov == bv && oi < bi)) { bv = ov; bi = oi; }
    }
    // all lanes now agree on bi (first index of min; index 0 if row all-inf,
    // matching jnp.argmin on an all-inf row)

    int f0 = (dup0 && a0 != bi) ? -100 : t0;
    int f1 = (dup1 && a1 != bi) ? -100 : t1;
    if (f0 >= 0) acc_agent[f0] = (unsigned char)(a0 + 1);  // 1..128; 0 = none
    if (f1 >= 0) acc_agent[f1] = (unsigned char)(a1 + 1);
}

// ---------------------------------------------------------------------------
// Kernel 3: table rewrite, float4-vectorized over the flat P*11 array.
// col 6: picked?2 : accepted?1 : old
// col 7: accepted? agent : old
// col 9: accepted? ts : old
// col10: picked?  ts : old        (ts = timesteps[row >> 9], K = 512)
// ---------------------------------------------------------------------------
__device__ __forceinline__ float update_elem(
    float x, unsigned int row, unsigned int col,
    const unsigned char* __restrict__ acc_agent,
    const unsigned char* __restrict__ picked,
    const int* __restrict__ timesteps)
{
    if (col < 6u || col == 8u) return x;
    if (col == 6u) {
        if (picked[row]) return 2.0f;
        unsigned char acc = acc_agent[row];
        if (acc) return 1.0f;
        return x;
    }
    if (col == 7u) {
        unsigned char acc = acc_agent[row];
        return acc ? (float)(acc - 1) : x;
    }
    if (col == 9u) {
        unsigned char acc = acc_agent[row];
        return acc ? (float)timesteps[row >> 9] : x;
    }
    // col == 10
    if (picked[row]) return (float)timesteps[row >> 9];
    return x;
}

__global__ __launch_bounds__(256) void k_update(
    const float4* __restrict__ in, float4* __restrict__ out,
    const unsigned char* __restrict__ acc_agent,
    const unsigned char* __restrict__ picked,
    const int* __restrict__ timesteps, int n4)
{
    int tid = blockIdx.x * 256 + threadIdx.x;
    if (tid >= n4) return;
    float4 x = in[tid];
    unsigned int base = (unsigned int)tid * 4u;
    unsigned int row = base / 11u;
    unsigned int col = base - row * 11u;

    float* xs = &x.x;
    #pragma unroll
    for (int j = 0; j < 4; ++j) {
        xs[j] = update_elem(xs[j], row, col, acc_agent, picked, timesteps);
        if (++col == 11u) { col = 0u; ++row; }
    }
    out[tid] = x;
}

// ---------------------------------------------------------------------------
extern "C" void kernel_launch(void* const* d_in, const int* in_sizes, int n_in,
                              void* d_out, int out_size, void* d_ws, size_t ws_size,
                              hipStream_t stream)
{
    const float* passengers = (const float*)d_in[0];
    const int*   accepts    = (const int*)d_in[1];
    const int*   picks      = (const int*)d_in[2];
    const int*   targets    = (const int*)d_in[3];
    const float* vectors    = (const float*)d_in[4];
    const int*   timesteps  = (const int*)d_in[5];
    float*       out        = (float*)d_out;

    // workspace layout (32 MB total):
    //   [0,            16M)  counts     int32  x P
    //   [16M,          20M)  acc_agent  uint8  x P
    //   [20M,          24M)  picked     uint8  x P
    //   [24M,          28M)  dist       f32    x E*A
    //   [28M,          32M)  accept_t   int32  x E*A
    char* ws = (char*)d_ws;
    int*            counts    = (int*)ws;
    unsigned char*  acc_agent = (unsigned char*)(ws + (size_t)P_TOT * 4);
    unsigned char*  picked    = acc_agent + P_TOT;
    float*          dist      = (float*)(ws + (size_t)P_TOT * 4 + 2 * (size_t)P_TOT);
    int*            accept_t  = (int*)(dist + E_ENV * A_AG);

    // zero counts + acc_agent + picked (ws is poisoned 0xAA each launch)
    hipMemsetAsync(ws, 0, (size_t)P_TOT * 4 + 2 * (size_t)P_TOT, stream);

    k_stage<<<E_ENV * A_AG / 256, 256, 0, stream>>>(
        accepts, picks, targets, (const float4*)vectors,
        counts, dist, accept_t, picked);

    k_resolve<<<E_ENV, 64, 0, stream>>>(counts, dist, accept_t, acc_agent);

    int n4 = P_TOT * 11 / 4;   // 11,534,336 (P*11 divisible by 4)
    k_update<<<(n4 + 255) / 256, 256, 0, stream>>>(
        (const float4*)passengers, (float4*)out, acc_agent, picked, timesteps, n4);
}

// Round 2
// 346.673 us; speedup vs baseline: 1.3008x; 1.3008x over previous
//
#include <hip/hip_runtime.h>

// Problem constants (fixed by the reference):
#define E_ENV 8192
#define A_AG  128
#define K_PASS 512
#define P_TOT (E_ENV * K_PASS)   // 4,194,304 passengers
#define N4    (P_TOT * 11 / 4)   // 11,534,336 float4s in the table

// ---------------------------------------------------------------------------
// Kernel 1: bulk copy passengers -> out. Pure float4 stream, ~6.3 TB/s.
// ---------------------------------------------------------------------------
__global__ __launch_bounds__(256) void k_copy(
    const float4* __restrict__ in, float4* __restrict__ out)
{
    int tid = blockIdx.x * 256 + threadIdx.x;   // grid sized exactly N4/256
    out[tid] = in[tid];
}

// ---------------------------------------------------------------------------
// Kernel 2: fused per-env stage + resolve + scatter. One block (128 threads,
// 2 waves) per env. Targets are env-partitioned -> all conflict state fits in
// a 512-entry LDS counter window; all writes go to this env's row range, so
// no cross-block races. The reference while_loop provably terminates after
// one body (every dup group is reduced to <=1 survivor), so one resolve pass.
//
// Write ordering (pick col6=2.0 must override accept col6=1.0): accept phase,
// __syncthreads() (drains vmcnt -> block-ordered global stores), pick phase.
// ---------------------------------------------------------------------------
__global__ __launch_bounds__(128) void k_env(
    const int* __restrict__ accepts, const int* __restrict__ picks,
    const int* __restrict__ targets, const float4* __restrict__ vectors,
    const int* __restrict__ timesteps, float* __restrict__ out)
{
    __shared__ int cnt[K_PASS];
    __shared__ float swv[2];
    __shared__ int   swi[2];

    const int e   = blockIdx.x;
    const int a   = threadIdx.x;        // agent 0..127
    const int gid = e * A_AG + a;

    // zero the per-env counter window
    #pragma unroll
    for (int j = 0; j < K_PASS / A_AG; ++j)
        cnt[a + j * A_AG] = 0;
    __syncthreads();

    // ---- stage ----
    float4 v = vectors[gid];
    bool invalid = (v.x == -100.0f) && (v.y == -100.0f) &&
                   (v.z == -100.0f) && (v.w == -100.0f);
    float dx = v.x - v.z, dy = v.y - v.w;
    float d = sqrtf(dx * dx + dy * dy);
    if (invalid) d = INFINITY;

    const int t     = targets[gid];          // global passenger id in [e*K,(e+1)*K)
    const int tl    = t - e * K_PASS;        // local 0..511
    const bool acc  = accepts[gid] != 0;
    const bool pick = picks[gid] != 0;

    int at = acc ? t : -100;
    if (at >= 0) atomicAdd(&cnt[tl], 1);
    __syncthreads();

    // ---- resolve (single iteration of the reference while_loop) ----
    bool dup = (at >= 0) && (cnt[tl] > 1);
    float bv = dup ? d : INFINITY;
    int   bi = a;

    // wave-64 butterfly argmin, first-index tie-break
    #pragma unroll
    for (int off = 32; off > 0; off >>= 1) {
        float ov = __shfl_xor(bv, off);
        int   oi = __shfl_xor(bi, off);
        if (ov < bv || (ov == bv && oi < bi)) { bv = ov; bi = oi; }
    }
    int wave = a >> 6;
    if ((a & 63) == 0) { swv[wave] = bv; swi[wave] = bi; }
    __syncthreads();
    float v0 = swv[0], v1 = swv[1];
    int   i0 = swi[0], i1 = swi[1];
    // tie -> smaller index (wave 0) wins: matches jnp.argmin first-index
    int bidx = (v1 < v0 || (v1 == v0 && i1 < i0)) ? i1 : i0;

    int f = (dup && a != bidx) ? -100 : at;

    const float tsf = (float)timesteps[e];

    // ---- accept scatter (<=1 surviving agent per passenger: plain stores) ----
    if (f >= 0) {
        size_t b = (size_t)f * 11;
        out[b + 6] = 1.0f;
        out[b + 7] = (float)a;
        out[b + 9] = tsf;
    }
    __syncthreads();   // order accept stores before pick stores (block fence)

    // ---- pick scatter (same-value multi-writers: benign) ----
    if (pick && d < 1e-6f) {
        size_t b = (size_t)t * 11;
        out[b + 6]  = 2.0f;
        out[b + 10] = tsf;
    }
}

// ---------------------------------------------------------------------------
extern "C" void kernel_launch(void* const* d_in, const int* in_sizes, int n_in,
                              void* d_out, int out_size, void* d_ws, size_t ws_size,
                              hipStream_t stream)
{
    const float* passengers = (const float*)d_in[0];
    const int*   accepts    = (const int*)d_in[1];
    const int*   picks      = (const int*)d_in[2];
    const int*   targets    = (const int*)d_in[3];
    const float* vectors    = (const float*)d_in[4];
    const int*   timesteps  = (const int*)d_in[5];
    float*       out        = (float*)d_out;

    // 1) bulk copy (N4 divisible by 256: 11,534,336 / 256 = 45,056 blocks)
    k_copy<<<N4 / 256, 256, 0, stream>>>((const float4*)passengers, (float4*)out);

    // 2) fused stage/resolve/scatter, one block per env
    k_env<<<E_ENV, A_AG, 0, stream>>>(accepts, picks, targets,
                                      (const float4*)vectors, timesteps, out);
}